// Round 7
// baseline (112.802 us; speedup 1.0000x reference)
//
#include <hip/hip_runtime.h>
#include <math.h>
#include <stdint.h>

#define NN 7
#define HD 128
#define FIN 32
#define TPB 8            // 8 tokens per block; 4 waves, each owns 2 tokens
#define LN_EPS 1e-5f
#define ALPHA 0.2f
#define NEG_CONST -9e15f
#define SCALE 0.08838834764831845f  // 128^-0.5

typedef __bf16 bf16x8 __attribute__((ext_vector_type(8)));
typedef float  f32x4  __attribute__((ext_vector_type(4)));

// intra-wave LDS ordering; sched_barrier stops hoisting past the wait (rule #18)
#define FENCE() do { asm volatile("s_waitcnt lgkmcnt(0)" ::: "memory"); \
                     __builtin_amdgcn_sched_barrier(0); } while (0)

__device__ __forceinline__ uint16_t f2bf_u(float f) {
    union { float f; uint32_t u; } v; v.f = f;
    uint32_t r = v.u + 0x7FFFu + ((v.u >> 16) & 1u);  // RNE
    return (uint16_t)(r >> 16);
}
__device__ __forceinline__ uint32_t pack2(float a, float b) {
    return (uint32_t)f2bf_u(a) | ((uint32_t)f2bf_u(b) << 16);
}
__device__ __forceinline__ float bflo(uint32_t u) {
    union { uint32_t q; float f; } v; v.q = u << 16; return v.f;
}
__device__ __forceinline__ float bfhi(uint32_t u) {
    union { uint32_t q; float f; } v; v.q = u & 0xffff0000u; return v.f;
}

// ws layout (bytes): WpT[7*128][32] bf16 @0 | W1T[128][128] bf16 @57344
// | W2T[128][128] bf16 @90112 | vab[2][2][128] f32 @122880
#define WS_W1T  57344
#define WS_W2T  90112
#define WS_VAB  122880

__global__ __launch_bounds__(256) void prep_weights(
    const float* __restrict__ Wp,
    const float* __restrict__ W1, const float* __restrict__ a1,
    const float* __restrict__ W2, const float* __restrict__ a2,
    uint16_t* __restrict__ WpT, uint16_t* __restrict__ W1T,
    uint16_t* __restrict__ W2T, float* __restrict__ vab)
{
    const int bid = blockIdx.x, tid = threadIdx.x;
    if (bid < 112) {                 // WpT[gc][f] = Wp[f][gc]
        int idx = bid * 256 + tid;
        int gc = idx >> 5, f = idx & 31;
        WpT[idx] = f2bf_u(Wp[(size_t)f * (NN * HD) + gc]);
    } else if (bid < 176) {          // W1T[c][k] = W1[k][c]
        int idx = (bid - 112) * 256 + tid;
        int c = idx >> 7, k = idx & 127;
        W1T[idx] = f2bf_u(W1[(size_t)k * HD + c]);
    } else if (bid < 240) {          // W2T[c][k] = W2[k][c]
        int idx = (bid - 176) * 256 + tid;
        int c = idx >> 7, k = idx & 127;
        W2T[idx] = f2bf_u(W2[(size_t)k * HD + c]);
    } else {                         // vab[l][which][j] = sum_o W[j][o]*a[which*128+o]
        for (int d = tid; d < 512; d += 256) {
            int l = d >> 8, which = (d >> 7) & 1, j = d & 127;
            const float* W = l ? W2 : W1;
            const float* a = (l ? a2 : a1) + which * HD;
            const float* row = W + (size_t)j * HD;
            float acc = 0.f;
            #pragma unroll 8
            for (int o = 0; o < HD; o += 4) {
                f32x4 wv = *reinterpret_cast<const f32x4*>(&row[o]);
                acc += wv[0]*a[o] + wv[1]*a[o+1] + wv[2]*a[o+2] + wv[3]*a[o+3];
            }
            vab[d] = acc;
        }
    }
}

__global__ __launch_bounds__(256, 8) void gat_fused(
    const float* __restrict__ x, const float* __restrict__ adj,
    const float* __restrict__ bp,
    const uint16_t* __restrict__ WpT, const uint16_t* __restrict__ W1T,
    const uint16_t* __restrict__ W2T, const float* __restrict__ vab,
    const float* __restrict__ g1, const float* __restrict__ b1,
    const float* __restrict__ g2, const float* __restrict__ b2,
    float* __restrict__ out, int BT)
{
    // SINGLE per-wave LDS buffer: bf16 residual h, RMW'd in place each layer.
    __shared__ __align__(16) uint16_t h_s[4][14][136];  // 15232 B -> 8 blocks/CU

    const int tid  = threadIdx.x;
    const int lane = tid & 63;
    const int wave = tid >> 6;
    const int frow = lane & 15;
    const int kgrp = lane >> 4;
    const int kb   = kgrp * 8;
    const int t0   = blockIdx.x * TPB;

    // per-lane attention-row identity: frow = tt*7 + np (frow 14,15 -> harmless dup)
    const int tt = (frow >= NN) ? 1 : 0;
    int np = frow - tt * NN; if (np > 6) np = 6;

    // adjacency row mask, once for both layers
    uint32_t amask = 0;
    #pragma unroll
    for (int j = 0; j < NN; ++j)
        amask |= (adj[np * NN + j] > 0.f) ? (1u << j) : 0u;

    // ---- B-frag: x for the block's 8 tokens (B col = token) ----
    bf16x8 bx;
    {
        union { bf16x8 v; uint32_t u[4]; } bu;
        bu.u[0] = bu.u[1] = bu.u[2] = bu.u[3] = 0;
        int tok = t0 + frow;
        if (frow < TPB && tok < BT) {
            f32x4 xa = *reinterpret_cast<const f32x4*>(&x[(size_t)tok * FIN + kb]);
            f32x4 xb = *reinterpret_cast<const f32x4*>(&x[(size_t)tok * FIN + kb + 4]);
            bu.u[0] = pack2(xa[0], xa[1]);
            bu.u[1] = pack2(xa[2], xa[3]);
            bu.u[2] = pack2(xb[0], xb[1]);
            bu.u[3] = pack2(xb[2], xb[3]);
        }
        bx = bu.v;
    }

    // ---- cooperative projection: 14 tiles/wave, h rows written bf16 (cross-wave) ----
    #pragma unroll 2
    for (int i = 0; i < 14; ++i) {
        int tile = wave * 14 + i;
        bf16x8 av = *reinterpret_cast<const bf16x8*>(WpT + (size_t)(tile * 16 + frow) * FIN + kb);
        f32x4 acc = {0.f, 0.f, 0.f, 0.f};
        acc = __builtin_amdgcn_mfma_f32_16x16x32_bf16(av, bx, acc, 0, 0, 0);
        int tok = t0 + frow;                 // C col = token, C row = out-col
        if (frow < TPB && tok < BT) {
            int gc0 = tile * 16 + kgrp * 4;  // 4 consecutive out-cols, same node
            f32x4 bias = *reinterpret_cast<const f32x4*>(&bp[gc0]);
            uint2 uu = { pack2(acc[0] + bias[0], acc[1] + bias[1]),
                         pack2(acc[2] + bias[2], acc[3] + bias[3]) };
            int n = gc0 >> 7, kk = gc0 & 127;
            *reinterpret_cast<uint2*>(&h_s[frow >> 1][(frow & 1) * NN + n][kk]) = uu;
        }
    }
    __syncthreads();   // the only block barrier

    for (int l = 0; l < 2; ++l) {
        const uint16_t* __restrict__ WT  = l ? W2T : W1T;
        const float*    __restrict__ vv0 = vab + l * 256;
        const float*    __restrict__ gg  = l ? g2 : g1;
        const float*    __restrict__ bb  = l ? b2 : b1;

        // ---- phase A: f-dots. slot=lane>>1 (0-13: f_src rows, 16-29: f_dst rows) ----
        float facc = 0.f;
        {
            int slot = lane >> 1, half = lane & 1;
            int which = (slot >> 4) & 1;
            int row = slot & 15; if (row > 13) row = 13;
            const uint32_t* hr = reinterpret_cast<const uint32_t*>(&h_s[wave][row][half * 64]);
            const f32x4* vp = reinterpret_cast<const f32x4*>(vv0 + which * HD + half * 64);
            #pragma unroll
            for (int i2 = 0; i2 < 8; ++i2) {
                uint4 hv = *reinterpret_cast<const uint4*>(hr + i2 * 4);
                f32x4 w0 = vp[2 * i2], w1 = vp[2 * i2 + 1];
                facc += bflo(hv.x)*w0[0] + bfhi(hv.x)*w0[1]
                      + bflo(hv.y)*w0[2] + bfhi(hv.y)*w0[3]
                      + bflo(hv.z)*w1[0] + bfhi(hv.z)*w1[1]
                      + bflo(hv.w)*w1[2] + bfhi(hv.w)*w1[3];
            }
            facc += __shfl_xor(facc, 1, 64);   // combine halves (full EXEC)
        }

        // ---- phase B: per-lane softmax for row (tt,np); all shfl full-EXEC ----
        float p[NN];
        {
            float fs = __shfl(facc, 2 * (tt * NN + np), 64);
            float e[NN]; float mx = -INFINITY;
            #pragma unroll
            for (int j = 0; j < NN; ++j) {
                float fd = __shfl(facc, 32 + 2 * (tt * NN + j), 64);
                float v = fs + fd;
                v = (v > 0.f ? v : ALPHA * v) * SCALE;
                v = ((amask >> j) & 1u) ? v : NEG_CONST;
                e[j] = v; mx = fmaxf(mx, v);
            }
            float ssum = 0.f;
            #pragma unroll
            for (int j = 0; j < NN; ++j) { e[j] = __expf(e[j] - mx); ssum += e[j]; }
            float inv = 1.f / ssum;
            #pragma unroll
            for (int j = 0; j < NN; ++j) p[j] = e[j] * inv;
        }

        // ---- phase C: g[frow][kb+ks*32..+7] = sum_j p[j]*h[tt*7+j][...] ----
        //      direct A-fragment build; 8 distinct LDS addrs/wave -> broadcast reads
        bf16x8 av4[4];
        #pragma unroll
        for (int ks = 0; ks < 4; ++ks) {
            float ga[8] = {0.f,0.f,0.f,0.f,0.f,0.f,0.f,0.f};
            #pragma unroll
            for (int j = 0; j < NN; ++j) {
                uint4 hj = *reinterpret_cast<const uint4*>(&h_s[wave][tt * NN + j][ks * 32 + kb]);
                float pj = p[j];
                ga[0] += pj * bflo(hj.x); ga[1] += pj * bfhi(hj.x);
                ga[2] += pj * bflo(hj.y); ga[3] += pj * bfhi(hj.y);
                ga[4] += pj * bflo(hj.z); ga[5] += pj * bfhi(hj.z);
                ga[6] += pj * bflo(hj.w); ga[7] += pj * bfhi(hj.w);
            }
            union { bf16x8 v; uint32_t u[4]; } bu;
            bu.u[0] = pack2(ga[0], ga[1]); bu.u[1] = pack2(ga[2], ga[3]);
            bu.u[2] = pack2(ga[4], ga[5]); bu.u[3] = pack2(ga[6], ga[7]);
            av4[ks] = bu.v;
        }

        // ---- phase D: GEMM hp = g @ W ; B-frags from global (L1/L2-hot) ----
        f32x4 Cacc[8];
        #pragma unroll
        for (int ntl = 0; ntl < 8; ++ntl) {
            const uint16_t* bpg = WT + (size_t)(ntl * 16 + frow) * HD + kb;
            f32x4 acc = {0.f, 0.f, 0.f, 0.f};
            #pragma unroll
            for (int ks = 0; ks < 4; ++ks) {
                bf16x8 bv = *reinterpret_cast<const bf16x8*>(bpg + ks * 32);
                acc = __builtin_amdgcn_mfma_f32_16x16x32_bf16(av4[ks], bv, acc, 0, 0, 0);
            }
            Cacc[ntl] = acc;
        }

        // ---- phase E: LayerNorm + residual, bf16 RMW on h (h never clobbered) ----
        {
            float mean4[4], rinv4[4];
            #pragma unroll
            for (int r = 0; r < 4; ++r) {
                float s = 0.f, sq = 0.f;
                #pragma unroll
                for (int q = 0; q < 8; ++q) { float c = Cacc[q][r]; s += c; sq += c * c; }
                #pragma unroll
                for (int mk = 1; mk <= 8; mk <<= 1) {
                    s  += __shfl_xor(s,  mk, 64);
                    sq += __shfl_xor(sq, mk, 64);
                }
                float mean = s * (1.f / HD);
                float var  = sq * (1.f / HD) - mean * mean;
                mean4[r] = mean;
                rinv4[r] = rsqrtf(var + LN_EPS);
            }
            #pragma unroll
            for (int q = 0; q < 8; ++q) {
                int col = q * 16 + frow;
                float gv = gg[col], bv = bb[col];
                #pragma unroll
                for (int r = 0; r < 4; ++r) {
                    int m = kgrp * 4 + r;
                    if (m < 14) {
                        uint16_t* hp = &h_s[wave][m][col];
                        float hold = bflo((uint32_t)*hp);
                        *hp = f2bf_u((Cacc[q][r] - mean4[r]) * rinv4[r] * gv + bv + hold);
                    }
                }
            }
        }
        FENCE();
    }

    // ---- out = mean over nodes (2 tokens per wave) ----
    {
        int t = lane >> 5, cq = lane & 31;
        int tok = t0 + wave * 2 + t;
        if (tok < BT) {
            f32x4 s = {0.f, 0.f, 0.f, 0.f};
            #pragma unroll
            for (int n = 0; n < NN; ++n) {
                uint2 hv = *reinterpret_cast<const uint2*>(&h_s[wave][t * NN + n][cq * 4]);
                s[0] += bflo(hv.x); s[1] += bfhi(hv.x);
                s[2] += bflo(hv.y); s[3] += bfhi(hv.y);
            }
            const float inv7 = 1.f / 7.f;
            f32x4 o = {s[0]*inv7, s[1]*inv7, s[2]*inv7, s[3]*inv7};
            *reinterpret_cast<f32x4*>(&out[(size_t)tok * HD + cq * 4]) = o;
        }
    }
}

extern "C" void kernel_launch(void* const* d_in, const int* in_sizes, int n_in,
                              void* d_out, int out_size, void* d_ws, size_t ws_size,
                              hipStream_t stream) {
    const float* x   = (const float*)d_in[0];
    const float* adj = (const float*)d_in[1];
    const float* Wp  = (const float*)d_in[2];
    const float* bp  = (const float*)d_in[3];
    const float* W1  = (const float*)d_in[4];
    const float* a1  = (const float*)d_in[5];
    const float* g1  = (const float*)d_in[6];
    const float* b1  = (const float*)d_in[7];
    const float* W2  = (const float*)d_in[8];
    const float* a2  = (const float*)d_in[9];
    const float* g2  = (const float*)d_in[10];
    const float* b2  = (const float*)d_in[11];
    const int BT = in_sizes[0] / FIN;
    const int blocks = (BT + TPB - 1) / TPB;

    uint8_t* ws = (uint8_t*)d_ws;
    uint16_t* WpT = (uint16_t*)(ws);
    uint16_t* W1T = (uint16_t*)(ws + WS_W1T);
    uint16_t* W2T = (uint16_t*)(ws + WS_W2T);
    float*    vab = (float*)   (ws + WS_VAB);

    prep_weights<<<dim3(241), dim3(256), 0, stream>>>(Wp, W1, a1, W2, a2,
                                                      WpT, W1T, W2T, vab);
    gat_fused<<<dim3(blocks), dim3(256), 0, stream>>>(
        x, adj, bp, WpT, W1T, W2T, vab, g1, b1, g2, b2, (float*)d_out, BT);
}

// Round 9
// 107.587 us; speedup vs baseline: 1.0485x; 1.0485x over previous
//
#include <hip/hip_runtime.h>
#include <math.h>
#include <stdint.h>

#define NN 7
#define HD 128
#define FIN 32
#define TPB 8            // 8 tokens per block; 4 waves, each owns 2 tokens
#define LN_EPS 1e-5f
#define ALPHA 0.2f
#define NEG_CONST -9e15f
#define SCALE 0.08838834764831845f  // 128^-0.5

typedef __bf16 bf16x8 __attribute__((ext_vector_type(8)));
typedef float  f32x4  __attribute__((ext_vector_type(4)));

// intra-wave LDS ordering; sched_barrier stops hoisting past the wait (rule #18)
#define FENCE() do { asm volatile("s_waitcnt lgkmcnt(0)" ::: "memory"); \
                     __builtin_amdgcn_sched_barrier(0); } while (0)

__device__ __forceinline__ uint16_t f2bf_u(float f) {
    union { float f; uint32_t u; } v; v.f = f;
    uint32_t r = v.u + 0x7FFFu + ((v.u >> 16) & 1u);  // RNE
    return (uint16_t)(r >> 16);
}
__device__ __forceinline__ uint32_t pack2(float a, float b) {
    return (uint32_t)f2bf_u(a) | ((uint32_t)f2bf_u(b) << 16);
}
__device__ __forceinline__ float bflo(uint32_t u) {
    union { uint32_t q; float f; } v; v.q = u << 16; return v.f;
}
__device__ __forceinline__ float bfhi(uint32_t u) {
    union { uint32_t q; float f; } v; v.q = u & 0xffff0000u; return v.f;
}

// DPP lane-reduce: ctrl must be an ICE -> template parameter
template <int CTRL>
__device__ __forceinline__ float dpp_add(float v) {
    union { float f; int i; } a, r;
    a.f = v;
    r.i = __builtin_amdgcn_update_dpp(a.i, a.i, CTRL, 0xF, 0xF, false);
    return v + r.f;
}
__device__ __forceinline__ float sum16(float v) {
    v = dpp_add<0xB1>(v);    // quad_perm [1,0,3,2] : xor 1
    v = dpp_add<0x4E>(v);    // quad_perm [2,3,0,1] : xor 2
    v = dpp_add<0x124>(v);   // row_ror:4
    v = dpp_add<0x128>(v);   // row_ror:8
    return v;
}

// ws layout (bytes):
//  WpTp[896][32] bf16 @0 | W1Tp[128][128] bf16 @57344 | W2Tp[128][128] bf16 @90112
//  | vabp[2][2][128] f32 @122880 | bpp[896] f32 @124928 | gbp[2][2][128] f32 @128512
#define WS_W1T  57344
#define WS_W2T  90112
#define WS_VAB  122880
#define WS_BPP  124928
#define WS_GBP  128512

__global__ __launch_bounds__(256) void prep_weights(
    const float* __restrict__ Wp, const float* __restrict__ bp,
    const float* __restrict__ W1, const float* __restrict__ a1,
    const float* __restrict__ g1, const float* __restrict__ b1,
    const float* __restrict__ W2, const float* __restrict__ a2,
    const float* __restrict__ g2, const float* __restrict__ b2,
    uint16_t* __restrict__ WpT, uint16_t* __restrict__ W1T,
    uint16_t* __restrict__ W2T, float* __restrict__ vab,
    float* __restrict__ bpp, float* __restrict__ gbp)
{
    const int bid = blockIdx.x, tid = threadIdx.x;
    if (bid < 112) {                 // WpTp[sig(gc)][f] = Wp[f][gc]
        int idx = bid * 256 + tid;
        int gc = idx >> 5, f = idx & 31;
        int gcp = (gc & ~127) | (((gc & 15) << 3) | ((gc & 127) >> 4));
        WpT[gcp * 32 + f] = f2bf_u(Wp[(size_t)f * (NN * HD) + gc]);
    } else if (bid < 176) {          // W1Tp[c][sig(k)] = W1[k][c]
        int idx = (bid - 112) * 256 + tid;
        int c = idx >> 7, k = idx & 127;
        int kp = ((k & 15) << 3) | (k >> 4);
        W1T[c * 128 + kp] = f2bf_u(W1[(size_t)k * HD + c]);
    } else if (bid < 240) {          // W2Tp[c][sig(k)] = W2[k][c]
        int idx = (bid - 176) * 256 + tid;
        int c = idx >> 7, k = idx & 127;
        int kp = ((k & 15) << 3) | (k >> 4);
        W2T[c * 128 + kp] = f2bf_u(W2[(size_t)k * HD + c]);
    } else {
        // vabp[l][which][sig(j)] = sum_o W[j][o]*a[which*128+o]
        for (int d = tid; d < 512; d += 256) {
            int l = d >> 8, which = (d >> 7) & 1, j = d & 127;
            const float* W = l ? W2 : W1;
            const float* a = (l ? a2 : a1) + which * HD;
            const float* row = W + (size_t)j * HD;
            float acc = 0.f;
            #pragma unroll 8
            for (int o = 0; o < HD; o += 4) {
                f32x4 wv = *reinterpret_cast<const f32x4*>(&row[o]);
                acc += wv[0]*a[o] + wv[1]*a[o+1] + wv[2]*a[o+2] + wv[3]*a[o+3];
            }
            int jp = ((j & 15) << 3) | (j >> 4);
            vab[l * 256 + which * 128 + jp] = acc;
        }
        // bpp[sig_g(gc)] = bp[gc]
        for (int gc = tid; gc < NN * HD; gc += 256) {
            int gcp = (gc & ~127) | (((gc & 15) << 3) | ((gc & 127) >> 4));
            bpp[gcp] = bp[gc];
        }
        // gbp[l][{g,b}][sig(c)]
        for (int e = tid; e < 512; e += 256) {
            int l = e >> 8, which = (e >> 7) & 1, c = e & 127;
            const float* src = l ? (which ? b2 : g2) : (which ? b1 : g1);
            int cp = ((c & 15) << 3) | (c >> 4);
            gbp[l * 256 + which * 128 + cp] = src[c];
        }
    }
}

__global__ __launch_bounds__(256, 5) void gat_fused(
    const float* __restrict__ x, const float* __restrict__ adj,
    const float* __restrict__ bpp,
    const uint16_t* __restrict__ WpT, const uint16_t* __restrict__ W1T,
    const uint16_t* __restrict__ W2T, const float* __restrict__ vab,
    const float* __restrict__ gbp,
    float* __restrict__ out, int BT)
{
    // single per-wave LDS buffer, sigma-permuted columns; rows padded to 16
    __shared__ __align__(16) uint16_t h_s[4][16][136];  // 17408 B

    const int tid  = threadIdx.x;
    const int lane = tid & 63;
    const int wave = tid >> 6;
    const int frow = lane & 15;
    const int kgrp = lane >> 4;
    const int kb   = kgrp * 8;
    const int t0   = blockIdx.x * TPB;

    // per-lane attention-row identity (frow 14,15 -> harmless dup of row 13)
    const int tt = (frow >= NN) ? 1 : 0;
    int np = frow - tt * NN; if (np > 6) np = 6;

    uint32_t amask = 0;
    #pragma unroll
    for (int j = 0; j < NN; ++j)
        amask |= (adj[np * NN + j] > 0.f) ? (1u << j) : 0u;

    // ---- B-frag: x for the block's 8 tokens (B col = token) ----
    bf16x8 bx;
    {
        union { bf16x8 v; uint32_t u[4]; } bu;
        bu.u[0] = bu.u[1] = bu.u[2] = bu.u[3] = 0;
        int tok = t0 + frow;
        if (frow < TPB && tok < BT) {
            f32x4 xa = *reinterpret_cast<const f32x4*>(&x[(size_t)tok * FIN + kb]);
            f32x4 xb = *reinterpret_cast<const f32x4*>(&x[(size_t)tok * FIN + kb + 4]);
            bu.u[0] = pack2(xa[0], xa[1]);
            bu.u[1] = pack2(xa[2], xa[3]);
            bu.u[2] = pack2(xb[0], xb[1]);
            bu.u[3] = pack2(xb[2], xb[3]);
        }
        bx = bu.v;
    }

    // ---- cooperative projection (WpT rows pre-sorted in sigma space) ----
    #pragma unroll 2
    for (int i = 0; i < 14; ++i) {
        int tile = wave * 14 + i;
        bf16x8 av = *reinterpret_cast<const bf16x8*>(WpT + (size_t)(tile * 16 + frow) * FIN + kb);
        f32x4 acc = {0.f, 0.f, 0.f, 0.f};
        acc = __builtin_amdgcn_mfma_f32_16x16x32_bf16(av, bx, acc, 0, 0, 0);
        int tok = t0 + frow;                 // C col = token, C row = out-col'
        if (frow < TPB && tok < BT) {
            int gc0 = tile * 16 + kgrp * 4;  // 4 consecutive sigma-cols, same node
            f32x4 bias = *reinterpret_cast<const f32x4*>(&bpp[gc0]);
            uint2 uu = { pack2(acc[0] + bias[0], acc[1] + bias[1]),
                         pack2(acc[2] + bias[2], acc[3] + bias[3]) };
            int n = gc0 >> 7, kk = gc0 & 127;
            *reinterpret_cast<uint2*>(&h_s[frow >> 1][(frow & 1) * NN + n][kk]) = uu;
        }
    }
    __syncthreads();   // the only block barrier

    for (int l = 0; l < 2; ++l) {
        const uint16_t* __restrict__ WT  = l ? W2T : W1T;
        const float*    __restrict__ vv0 = vab + l * 256;
        const float*    __restrict__ ggp = gbp + l * 256;  // [0..127]=gamma', [128..255]=beta'

        // ---- phase A: f-dots (slot = lane>>1; 0-13 f_src rows, 16-29 f_dst rows) ----
        float facc = 0.f;
        {
            int slot = lane >> 1, half = lane & 1;
            int which = (slot >> 4) & 1;
            int row = slot & 15; if (row > 13) row = 13;
            const uint32_t* hr = reinterpret_cast<const uint32_t*>(&h_s[wave][row][half * 64]);
            const f32x4* vp = reinterpret_cast<const f32x4*>(vv0 + which * HD + half * 64);
            #pragma unroll
            for (int i2 = 0; i2 < 8; ++i2) {
                uint4 hv = *reinterpret_cast<const uint4*>(hr + i2 * 4);
                f32x4 w0 = vp[2 * i2], w1 = vp[2 * i2 + 1];
                facc += bflo(hv.x)*w0[0] + bfhi(hv.x)*w0[1]
                      + bflo(hv.y)*w0[2] + bfhi(hv.y)*w0[3]
                      + bflo(hv.z)*w1[0] + bfhi(hv.z)*w1[1]
                      + bflo(hv.w)*w1[2] + bfhi(hv.w)*w1[3];
            }
            facc = dpp_add<0xB1>(facc);   // combine half-pairs (xor 1, VALU pipe)
        }

        // ---- phase B: per-lane softmax for row (tt,np); shfl full-EXEC ----
        float p[NN];
        {
            float fs = __shfl(facc, 2 * (tt * NN + np), 64);
            float e[NN]; float mx = -INFINITY;
            #pragma unroll
            for (int j = 0; j < NN; ++j) {
                float fd = __shfl(facc, 32 + 2 * (tt * NN + j), 64);
                float v = fs + fd;
                v = (v > 0.f ? v : ALPHA * v) * SCALE;
                v = ((amask >> j) & 1u) ? v : NEG_CONST;
                e[j] = v; mx = fmaxf(mx, v);
            }
            float ssum = 0.f;
            #pragma unroll
            for (int j = 0; j < NN; ++j) { e[j] = __expf(e[j] - mx); ssum += e[j]; }
            float inv = 1.f / ssum;
            #pragma unroll
            for (int j = 0; j < NN; ++j) p[j] = e[j] * inv;
        }

        // ---- phase C: A-frag build g[frow][sig-cols] = sum_j p[j]*h[tt*7+j][..] ----
        bf16x8 av4[4];
        #pragma unroll
        for (int ks = 0; ks < 4; ++ks) {
            float ga[8] = {0.f,0.f,0.f,0.f,0.f,0.f,0.f,0.f};
            #pragma unroll
            for (int j = 0; j < NN; ++j) {
                uint4 hj = *reinterpret_cast<const uint4*>(&h_s[wave][tt * NN + j][ks * 32 + kb]);
                float pj = p[j];
                ga[0] += pj * bflo(hj.x); ga[1] += pj * bfhi(hj.x);
                ga[2] += pj * bflo(hj.y); ga[3] += pj * bfhi(hj.y);
                ga[4] += pj * bflo(hj.z); ga[5] += pj * bfhi(hj.z);
                ga[6] += pj * bflo(hj.w); ga[7] += pj * bfhi(hj.w);
            }
            union { bf16x8 v; uint32_t u[4]; } bu;
            bu.u[0] = pack2(ga[0], ga[1]); bu.u[1] = pack2(ga[2], ga[3]);
            bu.u[2] = pack2(ga[4], ga[5]); bu.u[3] = pack2(ga[6], ga[7]);
            av4[ks] = bu.v;
        }

        // ---- phase D: GEMM hp = g @ W  (k-space sigma-permuted on both sides) ----
        f32x4 Cacc[8];
        #pragma unroll
        for (int ntl = 0; ntl < 8; ++ntl) {
            const uint16_t* bpg = WT + (size_t)(ntl * 16 + frow) * HD + kb;
            f32x4 acc = {0.f, 0.f, 0.f, 0.f};
            #pragma unroll
            for (int ks = 0; ks < 4; ++ks) {
                bf16x8 bv = *reinterpret_cast<const bf16x8*>(bpg + ks * 32);
                acc = __builtin_amdgcn_mfma_f32_16x16x32_bf16(av4[ks], bv, acc, 0, 0, 0);
            }
            Cacc[ntl] = acc;
        }

        // ---- phase E: LayerNorm + residual; contiguous b128 RMW (sigma layout) ----
        {
            f32x4 gv0 = *reinterpret_cast<const f32x4*>(ggp + frow * 8);
            f32x4 gv1 = *reinterpret_cast<const f32x4*>(ggp + frow * 8 + 4);
            f32x4 bv0 = *reinterpret_cast<const f32x4*>(ggp + 128 + frow * 8);
            f32x4 bv1 = *reinterpret_cast<const f32x4*>(ggp + 128 + frow * 8 + 4);
            #pragma unroll
            for (int r = 0; r < 4; ++r) {
                float s = 0.f, sq = 0.f;
                #pragma unroll
                for (int q = 0; q < 8; ++q) { float c = Cacc[q][r]; s += c; sq += c * c; }
                s = sum16(s); sq = sum16(sq);   // DPP all-reduce over 16 frow-lanes
                float mean = s * (1.f / HD);
                float var  = sq * (1.f / HD) - mean * mean;
                float rinv = rsqrtf(var + LN_EPS);
                int m = kgrp * 4 + r;
                if (m < 14) {
                    uint16_t* hp = &h_s[wave][m][frow * 8];
                    uint4 hold = *reinterpret_cast<const uint4*>(hp);
                    float n0 = (Cacc[0][r]-mean)*rinv*gv0[0] + bv0[0] + bflo(hold.x);
                    float n1 = (Cacc[1][r]-mean)*rinv*gv0[1] + bv0[1] + bfhi(hold.x);
                    float n2 = (Cacc[2][r]-mean)*rinv*gv0[2] + bv0[2] + bflo(hold.y);
                    float n3 = (Cacc[3][r]-mean)*rinv*gv0[3] + bv0[3] + bfhi(hold.y);
                    float n4 = (Cacc[4][r]-mean)*rinv*gv1[0] + bv1[0] + bflo(hold.z);
                    float n5 = (Cacc[5][r]-mean)*rinv*gv1[1] + bv1[1] + bfhi(hold.z);
                    float n6 = (Cacc[6][r]-mean)*rinv*gv1[2] + bv1[2] + bflo(hold.w);
                    float n7 = (Cacc[7][r]-mean)*rinv*gv1[3] + bv1[3] + bfhi(hold.w);
                    uint4 w;
                    w.x = pack2(n0, n1); w.y = pack2(n2, n3);
                    w.z = pack2(n4, n5); w.w = pack2(n6, n7);
                    *reinterpret_cast<uint4*>(hp) = w;
                }
            }
        }
        FENCE();
    }

    // ---- out = mean over nodes; de-permute sigma columns on store ----
    {
        int t = lane >> 5, cq = lane & 31;
        int tok = t0 + wave * 2 + t;
        if (tok < BT) {
            int cp0 = cq * 4;                       // 4 consecutive sigma-cols
            float s0 = 0.f, s1 = 0.f, s2 = 0.f, s3 = 0.f;
            #pragma unroll
            for (int n = 0; n < NN; ++n) {
                uint2 hv = *reinterpret_cast<const uint2*>(&h_s[wave][t * NN + n][cp0]);
                s0 += bflo(hv.x); s1 += bfhi(hv.x);
                s2 += bflo(hv.y); s3 += bfhi(hv.y);
            }
            const float inv7 = 1.f / 7.f;
            float* ob = out + (size_t)tok * HD;
            // inverse: c = (cp&7)*16 + (cp>>3)
            ob[((cp0    ) & 7) * 16 + ((cp0    ) >> 3)] = s0 * inv7;
            ob[((cp0 + 1) & 7) * 16 + ((cp0 + 1) >> 3)] = s1 * inv7;
            ob[((cp0 + 2) & 7) * 16 + ((cp0 + 2) >> 3)] = s2 * inv7;
            ob[((cp0 + 3) & 7) * 16 + ((cp0 + 3) >> 3)] = s3 * inv7;
        }
    }
}

extern "C" void kernel_launch(void* const* d_in, const int* in_sizes, int n_in,
                              void* d_out, int out_size, void* d_ws, size_t ws_size,
                              hipStream_t stream) {
    const float* x   = (const float*)d_in[0];
    const float* adj = (const float*)d_in[1];
    const float* Wp  = (const float*)d_in[2];
    const float* bp  = (const float*)d_in[3];
    const float* W1  = (const float*)d_in[4];
    const float* a1  = (const float*)d_in[5];
    const float* g1  = (const float*)d_in[6];
    const float* b1  = (const float*)d_in[7];
    const float* W2  = (const float*)d_in[8];
    const float* a2  = (const float*)d_in[9];
    const float* g2  = (const float*)d_in[10];
    const float* b2  = (const float*)d_in[11];
    const int BT = in_sizes[0] / FIN;
    const int blocks = (BT + TPB - 1) / TPB;

    uint8_t* ws = (uint8_t*)d_ws;
    uint16_t* WpT = (uint16_t*)(ws);
    uint16_t* W1T = (uint16_t*)(ws + WS_W1T);
    uint16_t* W2T = (uint16_t*)(ws + WS_W2T);
    float*    vab = (float*)   (ws + WS_VAB);
    float*    bpp = (float*)   (ws + WS_BPP);
    float*    gbp = (float*)   (ws + WS_GBP);

    prep_weights<<<dim3(241), dim3(256), 0, stream>>>(
        Wp, bp, W1, a1, g1, b1, W2, a2, g2, b2, WpT, W1T, W2T, vab, bpp, gbp);
    gat_fused<<<dim3(blocks), dim3(256), 0, stream>>>(
        x, adj, bpp, WpT, W1T, W2T, vab, gbp, (float*)d_out, BT);
}